// Round 1
// 90.800 us; speedup vs baseline: 1.0361x; 1.0361x over previous
//
#include <hip/hip_runtime.h>
#include <hip/hip_bf16.h>

typedef __attribute__((ext_vector_type(8))) short short8;
typedef __attribute__((ext_vector_type(4))) float float4v;
typedef __attribute__((ext_vector_type(4))) short short4v;

#define N_ROWS 4096
#define K_DIM  192
#define TILE   128
#define NT     32          // 4096/128 tiles per dim
#define NSYM   528         // 32*33/2 upper-triangular blocks
#define NBLK   2080        // 2*528 + 1024
#define C1     (-0.72134752044448179f)   // -0.5*log2(e)
#define LOG2E  (1.4426950408889634f)

// async global->LDS, 16B per lane; LDS dst is wave-uniform base + lane*16
__device__ __forceinline__ void gl16(const short* g, short* l)
{
    __builtin_amdgcn_global_load_lds((const __attribute__((address_space(1))) void*)g,
                                     (__attribute__((address_space(3))) void*)l,
                                     16, 0, 0);
}

// ---- kernel 1: fp32 -> bf16 convert + per-row sum of squares (of bf16 values) ----
// one row (192 f32) per wave: lanes 0..47 each handle a float4 -> short4
__global__ void prep_kernel(const float* __restrict__ x, const float* __restrict__ y,
                            __hip_bfloat16* __restrict__ xb, __hip_bfloat16* __restrict__ yb,
                            float* __restrict__ sqx, float* __restrict__ sqy)
{
    int w    = (blockIdx.x * blockDim.x + threadIdx.x) >> 6;  // global wave id = row id
    int lane = threadIdx.x & 63;
    if (w >= 2 * N_ROWS) return;
    const float* src = (w < N_ROWS) ? (x + (size_t)w * K_DIM) : (y + (size_t)(w - N_ROWS) * K_DIM);
    short*       dst = (short*)((w < N_ROWS) ? (xb + (size_t)w * K_DIM)
                                             : (yb + (size_t)(w - N_ROWS) * K_DIM));
    float s = 0.f;
    if (lane < 48) {                       // 192 = 48 lanes * 4
        float4v v = *(const float4v*)(src + lane * 4);
        short4v h;
        #pragma unroll
        for (int i = 0; i < 4; ++i) {
            __hip_bfloat16 b = __float2bfloat16(v[i]);
            h[i] = *(short*)&b;
            float fb = __bfloat162float(b);
            s += fb * fb;
        }
        *(short4v*)(dst + lane * 4) = h;
    }
    #pragma unroll
    for (int off = 32; off; off >>= 1) s += __shfl_down(s, off, 64);
    if (lane == 0) {
        if (w < N_ROWS) sqx[w] = s; else sqy[w - N_ROWS] = s;
    }
}

// ---- kernel 2: fused Gram + exp + block reduce ----
// block = 256 threads (4 waves, 2x2 quadrants of a 128x128 tile)
// K=192 in 6 stages of BK=32, double-buffered LDS, global_load_lds staging.
// LDS layout (per buffer): A[128][32] bf16 then B[128][32] bf16, linear rows of 4x16B
// chunks; chunk slot XOR-swizzled with (row&3) on BOTH the staged source address and
// the ds_read address (involution) -> conflict-free ds_read_b128.
__global__ __launch_bounds__(256) void gram_kernel(const __hip_bfloat16* __restrict__ xb,
                            const __hip_bfloat16* __restrict__ yb,
                            const float* __restrict__ sqx, const float* __restrict__ sqy,
                            float* __restrict__ partials)
{
    __shared__ short lds[16384];   // 2 buffers * (4096 A + 4096 B) shorts = 32 KB
    __shared__ float wred[4];

    const short* xbs = (const short*)xb;
    const short* ybs = (const short*)yb;

    int id = blockIdx.x;
    const short *A, *B; const float *sa, *sb;
    int bi, bj;
    float weight = 1.0f;
    if (id < 2 * NSYM) {
        int t;
        if (id < NSYM) { t = id;        A = xbs; B = xbs; sa = sqx; sb = sqx; }
        else           { t = id - NSYM; A = ybs; B = ybs; sa = sqy; sb = sqy; }
        bi = 0;
        while (t >= NT - bi) { t -= NT - bi; ++bi; }   // unrank upper triangle
        bj = bi + t;
        if (bi != bj) weight = 2.0f;                    // off-diagonal counts twice
    } else {
        int t = id - 2 * NSYM;
        bi = t >> 5; bj = t & 31;
        A = xbs; B = ybs; sa = sqx; sb = sqy;
    }
    const int abase = bi * TILE, bbase = bj * TILE;

    const int tid  = threadIdx.x;
    const int lane = tid & 63, w = tid >> 6;
    const int wm   = w >> 1,  wn = w & 1;
    const int m15  = lane & 15, quad = lane >> 4;

    // ---- staging constants ----
    // chunk index within a 256-chunk round = tid; row = tid>>2 (+64/round), slot = tid&3
    // LDS (row, slot) receives global chunk (slot ^ (row&3))   [involutive swizzle]
    const int crow = tid >> 2;
    const int xch  = (tid & 3) ^ (crow & 3);
    const short* srcA = A + (size_t)(abase + crow) * K_DIM + xch * 8;
    const short* srcB = B + (size_t)(bbase + crow) * K_DIM + xch * 8;

    // ---- read-side constants (swizzled ds_read_b128 offsets, in shorts) ----
    const int slotq = ((quad ^ (m15 & 3)) * 8);
    int aoff[4], boff[4];
    #pragma unroll
    for (int tm = 0; tm < 4; ++tm) aoff[tm] = (wm * 64 + tm * 16 + m15) * 32 + slotq;
    #pragma unroll
    for (int tn = 0; tn < 4; ++tn) boff[tn] = (wn * 64 + tn * 16 + m15) * 32 + slotq;

    float4v acc[4][4];
    #pragma unroll
    for (int i = 0; i < 4; ++i)
        #pragma unroll
        for (int j = 0; j < 4; ++j) acc[i][j] = (float4v){0.f, 0.f, 0.f, 0.f};

#define STAGE(p, k0)                                                         \
    {                                                                        \
        short* da = lds + (p) * 8192 + (tid & 0xC0) * 8;  /* + w*512 */      \
        gl16(srcA + (k0),               da);              /* rows  0..63  */ \
        gl16(srcA + (k0) + 64 * K_DIM,  da + 2048);       /* rows 64..127 */ \
        short* db = da + 4096;                                               \
        gl16(srcB + (k0),               db);                                 \
        gl16(srcB + (k0) + 64 * K_DIM,  db + 2048);                          \
    }

#define COMPUTE(p)                                                           \
    {                                                                        \
        const short* a0 = lds + (p) * 8192;                                  \
        const short* b0 = a0 + 4096;                                         \
        short8 af[4], bfr[4];                                                \
        _Pragma("unroll")                                                    \
        for (int tm = 0; tm < 4; ++tm) af[tm]  = *(const short8*)(a0 + aoff[tm]); \
        _Pragma("unroll")                                                    \
        for (int tn = 0; tn < 4; ++tn) bfr[tn] = *(const short8*)(b0 + boff[tn]); \
        _Pragma("unroll")                                                    \
        for (int tm = 0; tm < 4; ++tm)                                       \
            _Pragma("unroll")                                                \
            for (int tn = 0; tn < 4; ++tn)                                   \
                acc[tm][tn] = __builtin_amdgcn_mfma_f32_16x16x32_bf16(af[tm], bfr[tn], acc[tm][tn], 0, 0, 0); \
    }

    // 2-phase pipeline: issue next stage's loads, compute current, barrier
    // (__syncthreads drains vmcnt(0)+lgkmcnt(0): next buffer ready, current reads done)
    STAGE(0, 0)
    __syncthreads();
    #pragma unroll
    for (int s = 1; s <= 5; ++s) {
        STAGE(s & 1, s * 32)
        COMPUTE((s - 1) & 1)
        __syncthreads();
    }
    COMPUTE(1)

#undef STAGE
#undef COMPUTE

    // epilogue: e = exp2(min(C1*sqa + C1*sqb + log2e*g, 0)) == exp(-0.5*max(d2,0))
    float u[16], v[4];
    #pragma unroll
    for (int tm = 0; tm < 4; ++tm)
        #pragma unroll
        for (int r = 0; r < 4; ++r)
            u[tm * 4 + r] = C1 * sa[abase + wm * 64 + tm * 16 + quad * 4 + r];
    #pragma unroll
    for (int tn = 0; tn < 4; ++tn)
        v[tn] = C1 * sb[bbase + wn * 64 + tn * 16 + m15];

    float lsum = 0.f;
    #pragma unroll
    for (int tm = 0; tm < 4; ++tm)
        #pragma unroll
        for (int tn = 0; tn < 4; ++tn)
            #pragma unroll
            for (int r = 0; r < 4; ++r) {
                float g  = acc[tm][tn][r];
                float sv = fminf(u[tm * 4 + r] + v[tn] + LOG2E * g, 0.f);
                lsum += exp2f(sv);
            }

    #pragma unroll
    for (int off = 32; off; off >>= 1) lsum += __shfl_down(lsum, off, 64);
    if (lane == 0) wred[w] = lsum;
    __syncthreads();
    if (tid == 0) partials[id] = weight * (wred[0] + wred[1] + wred[2] + wred[3]);
}

// ---- kernel 3: final reduce + loss ----
__global__ void final_kernel(const float* __restrict__ partials, const float* __restrict__ avg_step,
                             float* __restrict__ out)
{
    __shared__ float red[3][4];
    int tid = threadIdx.x, lane = tid & 63, w = tid >> 6;
    float s0 = 0.f, s1 = 0.f, s2 = 0.f;
    for (int i = tid; i < NSYM; i += 256) s0 += partials[i];
    for (int i = tid; i < NSYM; i += 256) s1 += partials[NSYM + i];
    for (int i = tid; i < 1024; i += 256) s2 += partials[2 * NSYM + i];
    #pragma unroll
    for (int off = 32; off; off >>= 1) {
        s0 += __shfl_down(s0, off, 64);
        s1 += __shfl_down(s1, off, 64);
        s2 += __shfl_down(s2, off, 64);
    }
    if (lane == 0) { red[0][w] = s0; red[1][w] = s1; red[2][w] = s2; }
    __syncthreads();
    if (tid == 0) {
        float sxx = red[0][0] + red[0][1] + red[0][2] + red[0][3];
        float syy = red[1][0] + red[1][1] + red[1][2] + red[1][3];
        float sxy = red[2][0] + red[2][1] + red[2][2] + red[2][3];
        const float inv = 1.0f / 16777216.0f;   // 1/4096^2
        float XX = sxx * inv, YY = syy * inv, XY = sxy * inv;
        float mmd  = XX + YY - 2.0f * XY;
        float stepv = fmaxf(1.0f, avg_step[0]);
        float loss = mmd + (stepv - 1.0f) * 0.002f;
        out[0] = loss;
        out[1] = mmd;
    }
}

extern "C" void kernel_launch(void* const* d_in, const int* in_sizes, int n_in,
                              void* d_out, int out_size, void* d_ws, size_t ws_size,
                              hipStream_t stream)
{
    const float* x        = (const float*)d_in[0];
    const float* y        = (const float*)d_in[1];
    const float* avg_step = (const float*)d_in[2];

    char* ws = (char*)d_ws;
    // ws layout (16B-aligned chunks): xb | yb | sqx | sqy | partials  (~3.19 MB total)
    __hip_bfloat16* xb       = (__hip_bfloat16*)(ws);
    __hip_bfloat16* yb       = (__hip_bfloat16*)(ws + 1572864);
    float*          sqx      = (float*)(ws + 3145728);
    float*          sqy      = (float*)(ws + 3162112);
    float*          partials = (float*)(ws + 3178496);

    prep_kernel<<<2048, 256, 0, stream>>>(x, y, xb, yb, sqx, sqy);
    gram_kernel<<<NBLK, 256, 0, stream>>>(xb, yb, sqx, sqy, partials);
    final_kernel<<<1, 256, 0, stream>>>(partials, avg_step, (float*)d_out);
}